// Round 4
// baseline (204.244 us; speedup 1.0000x reference)
//
#include <hip/hip_runtime.h>

// CSR SpMV, 32 nnz/row exactly (uniform row_ptrs), ROWS=COLS=1e6.
//
// R4: 2 lanes per row -> 16 independent gathers per thread (deep MLP).
// row_ptrs read once per thread (rp[row + l2]) and exchanged via shfl_xor,
// cutting rp vector-path lane-slots 4x vs R2. Streams (vals/cols) stay
// non-temporal dwordx4 (16B/lane max) so x stays L2-resident.

typedef float f32x4 __attribute__((ext_vector_type(4)));
typedef int   i32x4 __attribute__((ext_vector_type(4)));

__global__ __launch_bounds__(256) void spmv_csr32_kernel(
    const float* __restrict__ x,
    const float* __restrict__ vals,
    const int*   __restrict__ cols,
    const int*   __restrict__ rp,
    float*       __restrict__ y,
    int rows)
{
    const int tid = blockIdx.x * blockDim.x + threadIdx.x;
    const int row = tid >> 1;   // 2 threads per row
    const int l2  = tid & 1;
    if (row >= rows) return;

    // one rp load per thread; exchange with partner lane
    const int mine  = __builtin_nontemporal_load(rp + row + l2);
    const int other = __shfl_xor(mine, 1);
    const int start = l2 ? other : mine;
    const int end   = l2 ? mine  : other;

    float sum = 0.0f;
    if (end - start == 32) {
        const int j = start + l2 * 4;   // this lane: nnz chunks j, j+8, j+16, j+24

        // indices first: all 16 gathers issued before any val use
        const i32x4 c0 = __builtin_nontemporal_load(reinterpret_cast<const i32x4*>(cols + j));
        const i32x4 c1 = __builtin_nontemporal_load(reinterpret_cast<const i32x4*>(cols + j + 8));
        const i32x4 c2 = __builtin_nontemporal_load(reinterpret_cast<const i32x4*>(cols + j + 16));
        const i32x4 c3 = __builtin_nontemporal_load(reinterpret_cast<const i32x4*>(cols + j + 24));

        const float x00 = x[c0[0]], x01 = x[c0[1]], x02 = x[c0[2]], x03 = x[c0[3]];
        const float x10 = x[c1[0]], x11 = x[c1[1]], x12 = x[c1[2]], x13 = x[c1[3]];
        const float x20 = x[c2[0]], x21 = x[c2[1]], x22 = x[c2[2]], x23 = x[c2[3]];
        const float x30 = x[c3[0]], x31 = x[c3[1]], x32 = x[c3[2]], x33 = x[c3[3]];

        const f32x4 v0 = __builtin_nontemporal_load(reinterpret_cast<const f32x4*>(vals + j));
        const f32x4 v1 = __builtin_nontemporal_load(reinterpret_cast<const f32x4*>(vals + j + 8));
        const f32x4 v2 = __builtin_nontemporal_load(reinterpret_cast<const f32x4*>(vals + j + 16));
        const f32x4 v3 = __builtin_nontemporal_load(reinterpret_cast<const f32x4*>(vals + j + 24));

        sum = v0[0]*x00 + v0[1]*x01 + v0[2]*x02 + v0[3]*x03
            + v1[0]*x10 + v1[1]*x11 + v1[2]*x12 + v1[3]*x13
            + v2[0]*x20 + v2[1]*x21 + v2[2]*x22 + v2[3]*x23
            + v3[0]*x30 + v3[1]*x31 + v3[2]*x32 + v3[3]*x33;
    } else {
        // general-CSR fallback (not hit for this input)
        for (int k = start + l2; k < end; k += 2)
            sum += vals[k] * x[cols[k]];
    }

    // reduce across the lane pair
    sum += __shfl_xor(sum, 1);

    if (l2 == 0) y[row] = sum;
}

extern "C" void kernel_launch(void* const* d_in, const int* in_sizes, int n_in,
                              void* d_out, int out_size, void* d_ws, size_t ws_size,
                              hipStream_t stream)
{
    const float* x    = (const float*)d_in[0];
    const float* vals = (const float*)d_in[1];
    const int*   cols = (const int*)d_in[2];
    const int*   rp   = (const int*)d_in[3];
    float*       y    = (float*)d_out;

    const int rows = out_size;              // 1,000,000
    const int threads = rows * 2;           // 2 lanes per row
    const int block = 256;
    const int grid = (threads + block - 1) / block;

    spmv_csr32_kernel<<<grid, block, 0, stream>>>(x, vals, cols, rp, y, rows);
}

// Round 5
// 197.597 us; speedup vs baseline: 1.0336x; 1.0336x over previous
//
#include <hip/hip_runtime.h>

// CSR SpMV, 32 nnz/row exactly (uniform row_ptrs), ROWS=COLS=1e6.
//
// R5: R2 structure (4 lanes/row, line-aligned NT stream loads) + x-gathers
// as inline-asm `global_load_dword vdst, voff, s[x] sc0`:
//   - sc0 bypasses L1 (no 128B line fill from L2 -> ~16x less L2->CU traffic)
//   - saddr form: 32-bit voffset (= col*4), no per-lane 64-bit address math
// All 12 VMEM ops issued, then one s_waitcnt vmcnt(0) + sched_barrier(0)
// before the FMA block (inline-asm loads inflate the compiler's vmcnt model
// conservatively -> its own waits only over-wait, never under-wait).

typedef float f32x4 __attribute__((ext_vector_type(4)));
typedef int   i32x4 __attribute__((ext_vector_type(4)));

__global__ __launch_bounds__(256) void spmv_csr32_kernel(
    const float* __restrict__ x,
    const float* __restrict__ vals,
    const int*   __restrict__ cols,
    const int*   __restrict__ rp,
    float*       __restrict__ y,
    int rows)
{
    const int tid  = blockIdx.x * blockDim.x + threadIdx.x;
    const int row  = tid >> 2;   // 4 threads per row
    const int l4   = tid & 3;
    if (row >= rows) return;

    const int start = rp[row];
    const int end   = rp[row + 1];

    float sum = 0.0f;
    if (end - start == 32) {
        const int j0 = start + l4 * 4;   // lanes cover [0..16) of the row
        const int j1 = j0 + 16;          // and [16..32)

        // Read-once index streams: NT dwordx4, per-instruction footprint is
        // exactly 4 aligned lines per wave (line-aligned; R4's wasn't).
        const i32x4 c0 = __builtin_nontemporal_load(reinterpret_cast<const i32x4*>(cols + j0));
        const i32x4 c1 = __builtin_nontemporal_load(reinterpret_cast<const i32x4*>(cols + j1));

        // 8 L1-bypass (sc0) dword gathers from x, issued back-to-back.
        float x0, x1, x2, x3, x4, x5, x6, x7;
        int o;
        #define GATHER(dst, cidx)                                              \
            o = (cidx) << 2;                                                   \
            asm volatile("global_load_dword %0, %1, %2 sc0"                    \
                         : "=v"(dst) : "v"(o), "s"(x) : "memory")
        GATHER(x0, c0[0]);
        GATHER(x1, c0[1]);
        GATHER(x2, c0[2]);
        GATHER(x3, c0[3]);
        GATHER(x4, c1[0]);
        GATHER(x5, c1[1]);
        GATHER(x6, c1[2]);
        GATHER(x7, c1[3]);
        #undef GATHER

        // Value streams issued while gathers are in flight.
        const f32x4 v0 = __builtin_nontemporal_load(reinterpret_cast<const f32x4*>(vals + j0));
        const f32x4 v1 = __builtin_nontemporal_load(reinterpret_cast<const f32x4*>(vals + j1));

        // Single drain, then fence so no consumer is hoisted above it.
        asm volatile("s_waitcnt vmcnt(0)" ::: "memory");
        __builtin_amdgcn_sched_barrier(0);

        sum = v0[0]*x0 + v0[1]*x1 + v0[2]*x2 + v0[3]*x3
            + v1[0]*x4 + v1[1]*x5 + v1[2]*x6 + v1[3]*x7;
    } else {
        // general-CSR fallback (not hit for this input)
        for (int k = start + l4; k < end; k += 4)
            sum += vals[k] * x[cols[k]];
    }

    // reduce across the 4-lane group
    sum += __shfl_xor(sum, 1);
    sum += __shfl_xor(sum, 2);

    if (l4 == 0) y[row] = sum;
}

extern "C" void kernel_launch(void* const* d_in, const int* in_sizes, int n_in,
                              void* d_out, int out_size, void* d_ws, size_t ws_size,
                              hipStream_t stream)
{
    const float* x    = (const float*)d_in[0];
    const float* vals = (const float*)d_in[1];
    const int*   cols = (const int*)d_in[2];
    const int*   rp   = (const int*)d_in[3];
    float*       y    = (float*)d_out;

    const int rows = out_size;              // 1,000,000
    const int threads = rows * 4;           // 4 lanes per row
    const int block = 256;
    const int grid = (threads + block - 1) / block;

    spmv_csr32_kernel<<<grid, block, 0, stream>>>(x, vals, cols, rp, y, rows);
}

// Round 7
// 195.574 us; speedup vs baseline: 1.0443x; 1.0103x over previous
//
#include <hip/hip_runtime.h>

// CSR SpMV, 32 nnz/row exactly (uniform row_ptrs), ROWS=COLS=1e6.
//
// R7: revert to R2 structure (best known: 187us) + three zero-risk tweaks:
//  - persistent grid-stride: 2048 blocks (8/CU), each looping over row-groups
//    of 64 -> no dispatch ramp of 15,625 short blocks
//  - __launch_bounds__(256, 8): allow full 8 waves/SIMD (VGPR is only ~16)
//  - row_ptr lane-pair exchange: 1 rp load/thread instead of 2
// Gathers stay plain f32 loads (R3 scope / R5 sc0 both proven neutral);
// streams stay NT dwordx4, line-aligned per instruction (R4 lesson).

typedef float f32x4 __attribute__((ext_vector_type(4)));
typedef int   i32x4 __attribute__((ext_vector_type(4)));

__global__ __launch_bounds__(256, 8) void spmv_csr32_kernel(
    const float* __restrict__ x,
    const float* __restrict__ vals,
    const int*   __restrict__ cols,
    const int*   __restrict__ rp,
    float*       __restrict__ y,
    int rows)
{
    const int l4  = threadIdx.x & 3;           // 4 lanes per row
    const int grp = threadIdx.x >> 2;          // row-within-group 0..63
    const int ngroups = rows >> 6;             // row-groups of 64 (1e6/64 = 15625 exact)

    for (int g = blockIdx.x; g < ngroups; g += gridDim.x) {
        const int row = (g << 6) + grp;

        // one rp load per thread; lane pairs (0,1) and (2,3) exchange
        const int mine  = rp[row + (l4 & 1)];
        const int other = __shfl_xor(mine, 1);
        const int start = (l4 & 1) ? other : mine;
        const int end   = (l4 & 1) ? mine  : other;

        float sum = 0.0f;
        if (end - start == 32) {
            const int j0 = start + l4 * 4;   // lanes cover [0..16) of the row
            const int j1 = j0 + 16;          // and [16..32)

            const i32x4 c0 = __builtin_nontemporal_load(reinterpret_cast<const i32x4*>(cols + j0));
            const i32x4 c1 = __builtin_nontemporal_load(reinterpret_cast<const i32x4*>(cols + j1));

            // 8 independent gathers, all issued before any use.
            const float x0 = x[c0[0]];
            const float x1 = x[c0[1]];
            const float x2 = x[c0[2]];
            const float x3 = x[c0[3]];
            const float x4 = x[c1[0]];
            const float x5 = x[c1[1]];
            const float x6 = x[c1[2]];
            const float x7 = x[c1[3]];

            const f32x4 v0 = __builtin_nontemporal_load(reinterpret_cast<const f32x4*>(vals + j0));
            const f32x4 v1 = __builtin_nontemporal_load(reinterpret_cast<const f32x4*>(vals + j1));

            sum = v0[0]*x0 + v0[1]*x1 + v0[2]*x2 + v0[3]*x3
                + v1[0]*x4 + v1[1]*x5 + v1[2]*x6 + v1[3]*x7;
        } else {
            // general-CSR fallback (not hit for this input)
            for (int k = start + l4; k < end; k += 4)
                sum += vals[k] * x[cols[k]];
        }

        // reduce across the 4-lane group
        sum += __shfl_xor(sum, 1);
        sum += __shfl_xor(sum, 2);

        if (l4 == 0) y[row] = sum;
    }
}

extern "C" void kernel_launch(void* const* d_in, const int* in_sizes, int n_in,
                              void* d_out, int out_size, void* d_ws, size_t ws_size,
                              hipStream_t stream)
{
    const float* x    = (const float*)d_in[0];
    const float* vals = (const float*)d_in[1];
    const int*   cols = (const int*)d_in[2];
    const int*   rp   = (const int*)d_in[3];
    float*       y    = (float*)d_out;

    const int rows = out_size;              // 1,000,000 (divisible by 64)
    const int block = 256;
    const int grid = 2048;                  // 8 blocks/CU, persistent grid-stride

    spmv_csr32_kernel<<<grid, block, 0, stream>>>(x, vals, cols, rp, y, rows);
}

// Round 8
// 184.625 us; speedup vs baseline: 1.1063x; 1.0593x over previous
//
#include <hip/hip_runtime.h>

// CSR SpMV, 32 nnz/row exactly (uniform row_ptrs), ROWS=COLS=1e6.
//
// R8 = R2 revert (best measured: 187us). Structural wall identified:
// ~36M random L2 line-requests (32M dword gathers + 4M stream lines) at
// a measured chip-wide service rate of ~0.2M requests/us -> ~180-190us.
// Verified request-rate model: R4 (+4M reqs -> +19us), R1 (+2.2M refill
// reqs -> +36us), R3/R5/R7 (same reqs -> null). Gather requests are
// irreducible for uniform-random column indices.
//
// Config: 4 lanes/row; NT dwordx4 streams (line-aligned per instruction,
// no L2 allocation so x stays L2-resident); plain f32 gathers; flat grid.

typedef float f32x4 __attribute__((ext_vector_type(4)));
typedef int   i32x4 __attribute__((ext_vector_type(4)));

__global__ __launch_bounds__(256) void spmv_csr32_kernel(
    const float* __restrict__ x,
    const float* __restrict__ vals,
    const int*   __restrict__ cols,
    const int*   __restrict__ rp,
    float*       __restrict__ y,
    int rows)
{
    const int tid  = blockIdx.x * blockDim.x + threadIdx.x;
    const int row  = tid >> 2;   // 4 threads per row
    const int l4   = tid & 3;
    if (row >= rows) return;

    const int start = rp[row];
    const int end   = rp[row + 1];

    float sum = 0.0f;
    if (end - start == 32) {
        const int j0 = start + l4 * 4;   // lanes cover [0..16) of the row
        const int j1 = j0 + 16;          // and [16..32)

        // Read-once streams: non-temporal (no L2 allocation -> x stays resident).
        const f32x4 v0 = __builtin_nontemporal_load(reinterpret_cast<const f32x4*>(vals + j0));
        const f32x4 v1 = __builtin_nontemporal_load(reinterpret_cast<const f32x4*>(vals + j1));
        const i32x4 c0 = __builtin_nontemporal_load(reinterpret_cast<const i32x4*>(cols + j0));
        const i32x4 c1 = __builtin_nontemporal_load(reinterpret_cast<const i32x4*>(cols + j1));

        // 8 independent gathers, all issued before any use (MLP).
        const float x0 = x[c0[0]];
        const float x1 = x[c0[1]];
        const float x2 = x[c0[2]];
        const float x3 = x[c0[3]];
        const float x4 = x[c1[0]];
        const float x5 = x[c1[1]];
        const float x6 = x[c1[2]];
        const float x7 = x[c1[3]];

        sum = v0[0]*x0 + v0[1]*x1 + v0[2]*x2 + v0[3]*x3
            + v1[0]*x4 + v1[1]*x5 + v1[2]*x6 + v1[3]*x7;
    } else {
        // general-CSR fallback (not hit for this input)
        for (int k = start + l4; k < end; k += 4)
            sum += vals[k] * x[cols[k]];
    }

    // reduce across the 4-lane group
    sum += __shfl_xor(sum, 1);
    sum += __shfl_xor(sum, 2);

    if (l4 == 0) y[row] = sum;
}

extern "C" void kernel_launch(void* const* d_in, const int* in_sizes, int n_in,
                              void* d_out, int out_size, void* d_ws, size_t ws_size,
                              hipStream_t stream)
{
    const float* x    = (const float*)d_in[0];
    const float* vals = (const float*)d_in[1];
    const int*   cols = (const int*)d_in[2];
    const int*   rp   = (const int*)d_in[3];
    float*       y    = (float*)d_out;

    const int rows = out_size;              // 1,000,000
    const int threads = rows * 4;           // 4 lanes per row
    const int block = 256;
    const int grid = (threads + block - 1) / block;

    spmv_csr32_kernel<<<grid, block, 0, stream>>>(x, vals, cols, rp, y, rows);
}